// Round 9
// baseline (325.556 us; speedup 1.0000x reference)
//
#include <hip/hip_runtime.h>
#include <hip/hip_fp16.h>

static constexpr int ID   = 128;    // IN_DIM
static constexpr int ND   = 32;     // NET_DIM
static constexpr int NPB  = 256;    // nodes per bucket (lc fits 8 bits)
static constexpr int BCAP = 8960;   // edge capacity per bucket segment (mean 8192 + 8.5 sigma)
static constexpr int CPAD = 16;     // u32 per bucket cursor (64B line)
static constexpr int EPB  = 8192;   // edges per k_place block
static constexpr int BMAX = 400;    // >= ceil(100000/256)=391

union H2U { __half2 h; float f; };
static __device__ __forceinline__ float pack2(float a, float b) {
    H2U z; z.h = __floats2half2_rn(a, b); return z.f;
}

// ---- init bucket cursors to segment bases ----
__global__ __launch_bounds__(512) void k_init(unsigned* __restrict__ bcur, int B) {
    int b = threadIdx.x;
    if (b < B) bcur[(size_t)b * CPAD] = (unsigned)b * BCAP;
}

// ---- two-phase binning into 256-node buckets with static segments ----
__global__ __launch_bounds__(256) void k_place(const int* __restrict__ row,
                                               const int* __restrict__ col,
                                               unsigned* __restrict__ bcur,
                                               unsigned* __restrict__ packed,
                                               int E, int B) {
    __shared__ unsigned lcnt[BMAX];
    __shared__ unsigned lbase[BMAX];
    int tid = threadIdx.x;
    for (int i = tid; i < B; i += 256) lcnt[i] = 0u;
    __syncthreads();
    long base = (long)blockIdx.x * EPB;
#pragma unroll
    for (int i = 0; i < EPB / 256; ++i) {
        long e = base + tid + (long)i * 256;
        if (e < E) atomicAdd(&lcnt[col[e] >> 8], 1u);
    }
    __syncthreads();
    for (int b = tid; b < B; b += 256) {
        unsigned v = lcnt[b];
        lbase[b] = v ? atomicAdd(&bcur[(size_t)b * CPAD], v) : 0u;  // absolute pos
        lcnt[b] = 0u;   // reuse as local cursor
    }
    __syncthreads();
#pragma unroll
    for (int i = 0; i < EPB / 256; ++i) {
        long e = base + tid + (long)i * 256;
        if (e < E) {
            int c = col[e];         // L2-hot second read
            int b = c >> 8;
            unsigned lofs = atomicAdd(&lcnt[b], 1u);
            packed[lbase[b] + lofs] = ((unsigned)(c & (NPB - 1)) << 17) | (unsigned)row[e];
        }
    }
}

// ---- bucket-local counting sort; emits meta(noff,cnt)/dinv for 256 nodes ----
__global__ __launch_bounds__(512) void k_bsort(const unsigned* __restrict__ bcur,
                                               const unsigned* __restrict__ packed,
                                               unsigned* __restrict__ srclist,
                                               uint2* __restrict__ meta,
                                               float* __restrict__ dinv, int n) {
    __shared__ unsigned lcnt[NPB];
    __shared__ unsigned loff[NPB];
    __shared__ unsigned lcur[NPB];
    __shared__ unsigned sscan[NPB];
    int b = blockIdx.x;
    int tid = threadIdx.x;
    if (tid < NPB) { lcnt[tid] = 0u; lcur[tid] = 0u; }
    __syncthreads();
    unsigned base = (unsigned)b * BCAP;
    unsigned m = bcur[(size_t)b * CPAD] - base;
    for (unsigned i = (unsigned)tid; i < m; i += 512u)
        atomicAdd(&lcnt[packed[base + i] >> 17], 1u);
    __syncthreads();
    if (tid < NPB) sscan[tid] = lcnt[tid];
    __syncthreads();
    for (int d = 1; d < NPB; d <<= 1) {
        unsigned v = 0u;
        if (tid < NPB && tid >= d) v = sscan[tid - d];
        __syncthreads();
        if (tid < NPB) sscan[tid] += v;
        __syncthreads();
    }
    if (tid < NPB) {
        unsigned v = lcnt[tid];
        unsigned excl = sscan[tid] - v;
        loff[tid] = excl;
        int node = b * NPB + tid;
        if (node < n) {
            meta[node] = make_uint2(base + excl, v);
            dinv[node] = rsqrtf((float)(v + 1u));
        }
    }
    __syncthreads();
    for (unsigned i = (unsigned)tid; i < m; i += 512u) {
        unsigned u = packed[base + i];
        unsigned lc = u >> 17;
        unsigned p = atomicAdd(&lcur[lc], 1u);
        srclist[base + loff[lc] + p] = u & 0x1FFFFu;
    }
}

// ---- hs_{lo,hi} = fp16( dinv[i] * (x[i] @ W_gcn) ), split 16+16 channels ----
__global__ __launch_bounds__(256) void k_gemm(const float* __restrict__ x,
                                              const float* __restrict__ W,
                                              const float* __restrict__ dinv,
                                              __half* __restrict__ hs_lo,
                                              __half* __restrict__ hs_hi, int n) {
    __shared__ float sW[ID * ND];        // 16 KB, [k][j]
    for (int i = threadIdx.x; i < ID * ND; i += 256) sW[i] = W[i];
    __syncthreads();
    int rowi = blockIdx.x * 256 + threadIdx.x;
    if (rowi >= n) return;
    const float4* sW4 = reinterpret_cast<const float4*>(sW);   // [k][8]
    float4 acc4[8];
#pragma unroll
    for (int q = 0; q < 8; ++q) acc4[q] = make_float4(0.f, 0.f, 0.f, 0.f);
    const float4* xr = reinterpret_cast<const float4*>(x + (size_t)rowi * ID);
    for (int k4 = 0; k4 < ID / 4; ++k4) {
        float4 xv = xr[k4];
        float xk[4] = {xv.x, xv.y, xv.z, xv.w};
#pragma unroll
        for (int kk = 0; kk < 4; ++kk) {
            int k = k4 * 4 + kk;
#pragma unroll
            for (int q = 0; q < 8; ++q) {
                float4 w = sW4[k * 8 + q];
                acc4[q].x += xk[kk] * w.x;
                acc4[q].y += xk[kk] * w.y;
                acc4[q].z += xk[kk] * w.z;
                acc4[q].w += xk[kk] * w.w;
            }
        }
    }
    float di = dinv[rowi];
    float4* lo4 = reinterpret_cast<float4*>(hs_lo + (size_t)rowi * 16);
    float4* hi4 = reinterpret_cast<float4*>(hs_hi + (size_t)rowi * 16);
#pragma unroll
    for (int h = 0; h < 2; ++h) {
        float4* dst = h ? hi4 : lo4;
#pragma unroll
        for (int p = 0; p < 2; ++p) {
            float4 a0 = acc4[h * 4 + p * 2];
            float4 a1 = acc4[h * 4 + p * 2 + 1];
            float4 f;
            f.x = pack2(di * a0.x, di * a0.y);
            f.y = pack2(di * a0.z, di * a0.w);
            f.z = pack2(di * a1.x, di * a1.y);
            f.w = pack2(di * a1.z, di * a1.w);
            dst[p] = f;
        }
    }
}

// ---- gather over 16 channels against an L2-resident 3.2MB half-table ----
// wave = 32 edge slots x 2 lanes x 16B; writes g = relu(dinv*acc + bg) fp16
__global__ __launch_bounds__(256) void k_gat(const uint2* __restrict__ meta,
                                             const unsigned* __restrict__ srclist,
                                             const __half* __restrict__ hs_half,
                                             const float* __restrict__ dinv,
                                             const float* __restrict__ bg_half,
                                             __half* __restrict__ g_half,
                                             int n, int nwaves) {
    int lane = threadIdx.x & 63;
    int wid = (int)((blockIdx.x * 256 + threadIdx.x) >> 6);
    int sub = lane >> 1;       // edge slot 0..31
    int l2  = lane & 1;        // which 16B half of the 32B row

    float4 bA = *reinterpret_cast<const float4*>(bg_half + l2 * 8);
    float4 bB = *reinterpret_cast<const float4*>(bg_half + l2 * 8 + 4);
    float bg8[8] = {bA.x, bA.y, bA.z, bA.w, bB.x, bB.y, bB.z, bB.w};

    const float4* t4 = reinterpret_cast<const float4*>(hs_half);   // row = 2 float4

    for (int c = wid; c < n; c += nwaves) {
        uint2 mt = meta[c];
        unsigned start = mt.x, deg = mt.y;
        float a[8];
#pragma unroll
        for (int j = 0; j < 8; ++j) a[j] = 0.f;
        for (unsigned k = 0; k < deg; k += 32u) {
            unsigned i = k + (unsigned)sub;
            bool g0 = i < deg;
            unsigned r = g0 ? srclist[start + i] : 0u;
            float4 v = t4[(size_t)r * 2 + l2];
            if (g0) {
                const __half2* hp = reinterpret_cast<const __half2*>(&v);
#pragma unroll
                for (int j = 0; j < 4; ++j) {
                    float2 f = __half22float2(hp[j]);
                    a[2 * j] += f.x; a[2 * j + 1] += f.y;
                }
            }
        }
        {   // self-loop, added once (sub==0 lane pair)
            float4 sv = t4[(size_t)c * 2 + l2];
            if (sub == 0) {
                const __half2* hp = reinterpret_cast<const __half2*>(&sv);
#pragma unroll
                for (int j = 0; j < 4; ++j) {
                    float2 f = __half22float2(hp[j]);
                    a[2 * j] += f.x; a[2 * j + 1] += f.y;
                }
            }
        }
#pragma unroll
        for (int st = 2; st <= 32; st <<= 1) {
#pragma unroll
            for (int j = 0; j < 8; ++j) a[j] += __shfl_xor(a[j], st);
        }
        if (sub == 0) {
            float di = dinv[c];
            float r0 = fmaxf(di * a[0] + bg8[0], 0.f);
            float r1 = fmaxf(di * a[1] + bg8[1], 0.f);
            float r2 = fmaxf(di * a[2] + bg8[2], 0.f);
            float r3 = fmaxf(di * a[3] + bg8[3], 0.f);
            float r4 = fmaxf(di * a[4] + bg8[4], 0.f);
            float r5 = fmaxf(di * a[5] + bg8[5], 0.f);
            float r6 = fmaxf(di * a[6] + bg8[6], 0.f);
            float r7 = fmaxf(di * a[7] + bg8[7], 0.f);
            float4 o;
            o.x = pack2(r0, r1); o.y = pack2(r2, r3);
            o.z = pack2(r4, r5); o.w = pack2(r6, r7);
            reinterpret_cast<float4*>(g_half)[(size_t)c * 2 + l2] = o;
        }
    }
}

// ---- dense: out = relu(g @ Wd + bd), thread per node ----
__global__ __launch_bounds__(256) void k_dense(const __half* __restrict__ g_lo,
                                               const __half* __restrict__ g_hi,
                                               const float* __restrict__ Wd,
                                               const float* __restrict__ bd,
                                               float* __restrict__ out, int n) {
    __shared__ float sW[ND * ND];   // [j][ch], 4 KB
    __shared__ float sbd[ND];
    for (int i = threadIdx.x; i < ND * ND; i += 256) sW[i] = Wd[i];
    if (threadIdx.x < ND) sbd[threadIdx.x] = bd[threadIdx.x];
    __syncthreads();
    int i = blockIdx.x * 256 + threadIdx.x;
    if (i >= n) return;
    float4 raw[4];
    raw[0] = reinterpret_cast<const float4*>(g_lo)[(size_t)i * 2];
    raw[1] = reinterpret_cast<const float4*>(g_lo)[(size_t)i * 2 + 1];
    raw[2] = reinterpret_cast<const float4*>(g_hi)[(size_t)i * 2];
    raw[3] = reinterpret_cast<const float4*>(g_hi)[(size_t)i * 2 + 1];
    float gf[32];
    const __half2* hp = reinterpret_cast<const __half2*>(raw);
#pragma unroll
    for (int q = 0; q < 16; ++q) {
        float2 f = __half22float2(hp[q]);
        gf[2 * q] = f.x; gf[2 * q + 1] = f.y;
    }
    const float4* sW4 = reinterpret_cast<const float4*>(sW);
    const float4* sbd4 = reinterpret_cast<const float4*>(sbd);
    float4 o4[8];
#pragma unroll
    for (int q = 0; q < 8; ++q) o4[q] = sbd4[q];
#pragma unroll
    for (int j = 0; j < 32; ++j) {
        float gj = gf[j];
#pragma unroll
        for (int q = 0; q < 8; ++q) {
            float4 w = sW4[j * 8 + q];
            o4[q].x += gj * w.x;
            o4[q].y += gj * w.y;
            o4[q].z += gj * w.z;
            o4[q].w += gj * w.w;
        }
    }
    float4* op = reinterpret_cast<float4*>(out + (size_t)i * ND);
#pragma unroll
    for (int q = 0; q < 8; ++q) {
        float4 o;
        o.x = fmaxf(o4[q].x, 0.f);
        o.y = fmaxf(o4[q].y, 0.f);
        o.z = fmaxf(o4[q].z, 0.f);
        o.w = fmaxf(o4[q].w, 0.f);
        op[q] = o;
    }
}

extern "C" void kernel_launch(void* const* d_in, const int* in_sizes, int n_in,
                              void* d_out, int out_size, void* d_ws, size_t ws_size,
                              hipStream_t stream) {
    const float* x  = (const float*)d_in[0];
    const int*   ei = (const int*)d_in[1];   // [2, E] flat: row then col
    const float* Wg = (const float*)d_in[2];
    const float* bg = (const float*)d_in[3];
    const float* Wd = (const float*)d_in[4];
    const float* bd = (const float*)d_in[5];
    float* out = (float*)d_out;

    const int n = in_sizes[0] / ID;        // 100000
    const int E = in_sizes[1] / 2;         // 3200000
    const int* erow = ei;
    const int* ecol = ei + E;
    const int B  = (n + NPB - 1) / NPB;    // 391 buckets
    const int nb = (n + 255) / 256;        // 391 node blocks
    const int ebl = (E + EPB - 1) / EPB;   // 391 binning blocks

    // workspace carve-up (~29.3 MB)
    unsigned* packed  = (unsigned*)d_ws;                     // B*BCAP u32 (14.0 MB)
    unsigned* srclist = packed + (size_t)B * BCAP;           // B*BCAP u32 (14.0 MB)
    uint2*    meta    = (uint2*)(srclist + (size_t)B * BCAP);// n uint2    (0.8 MB)
    float*    dinv    = (float*)(meta + n);                  // n f32      (0.4 MB)
    unsigned* bcur    = (unsigned*)(dinv + n);               // B*CPAD u32 (25 KB)
    // aliases into packed region (dead after k_bsort): 4 x 3.2MB = 12.8 <= 14.0
    __half* hs_lo = (__half*)packed;
    __half* hs_hi = hs_lo + (size_t)n * 16;
    __half* g_lo  = hs_hi + (size_t)n * 16;
    __half* g_hi  = g_lo  + (size_t)n * 16;

    k_init<<<1, 512, 0, stream>>>(bcur, B);
    k_place<<<ebl, 256, 0, stream>>>(erow, ecol, bcur, packed, E, B);
    k_bsort<<<B, 512, 0, stream>>>(bcur, packed, srclist, meta, dinv, n);
    k_gemm<<<nb, 256, 0, stream>>>(x, Wg, dinv, hs_lo, hs_hi, n);
    k_gat<<<2048, 256, 0, stream>>>(meta, srclist, hs_lo, dinv, bg,      g_lo, n, 2048 * 4);
    k_gat<<<2048, 256, 0, stream>>>(meta, srclist, hs_hi, dinv, bg + 16, g_hi, n, 2048 * 4);
    k_dense<<<nb, 256, 0, stream>>>(g_lo, g_hi, Wd, bd, out, n);
}